// Round 2
// baseline (158.527 us; speedup 1.0000x reference)
//
#include <hip/hip_runtime.h>

#define BB 8
#define TT 128
#define DD 256
#define BT (BB * TT)        // 1024 (b,t) pairs
#define LOG2E 1.44269504088896340736f

// Phase 1 (R7): one block per (b,t). The key identity: colsum and rowsum are
// the column-sums and row-sums of the SAME 256x256 matrix M[p][q]=exp(d_p*e_q)
// -- previous rounds computed every element TWICE (symmetric recompute).
// Here each thread owns a 16x16 tile of M: 256 exps, accumulating 16 row
// partials and 16 col partials in registers (static indexing only -- no
// scratch). Exp count halves: 134M -> 67M. R6 taught us phase1 is
// issue-bound on the instruction stream (adding bpermutes cost exactly their
// issue time), so halving the dominant instruction class should halve phase1.
// Cross-thread combine via two cheap LDS passes (512 outputs, 16 partials
// each -- negligible vs 65536 exps/block).
__global__ __launch_bounds__(256, 4) void attn_tile_kernel(
    const float* __restrict__ dec,   // [B, D]
    const float* __restrict__ enc,   // [B, T, D]
    float* __restrict__ ws) {        // [BT, D] per-(b,t) contributions
    const int blk = blockIdx.x;              // b*TT + t
    const int b = blk >> 7;
    const int tid = threadIdx.x;
    const int ti = tid >> 4;                 // row-block i  (p in [16*ti, +16))
    const int tj = tid & 15;                 // col-block j  (q in [16*tj, +16))

    const float* __restrict__ drow = dec + b * DD;
    const float* __restrict__ erow = enc + blk * DD;

    // Load this tile's operands: 16 d-rows, 16 e-cols (pre-scaled by LOG2E).
    float d[16], el2[16];
    {
        float4 v;
        v = *reinterpret_cast<const float4*>(drow + ti * 16 + 0);
        d[0] = v.x; d[1] = v.y; d[2] = v.z; d[3] = v.w;
        v = *reinterpret_cast<const float4*>(drow + ti * 16 + 4);
        d[4] = v.x; d[5] = v.y; d[6] = v.z; d[7] = v.w;
        v = *reinterpret_cast<const float4*>(drow + ti * 16 + 8);
        d[8] = v.x; d[9] = v.y; d[10] = v.z; d[11] = v.w;
        v = *reinterpret_cast<const float4*>(drow + ti * 16 + 12);
        d[12] = v.x; d[13] = v.y; d[14] = v.z; d[15] = v.w;
        v = *reinterpret_cast<const float4*>(erow + tj * 16 + 0);
        el2[0] = v.x * LOG2E; el2[1] = v.y * LOG2E; el2[2] = v.z * LOG2E; el2[3] = v.w * LOG2E;
        v = *reinterpret_cast<const float4*>(erow + tj * 16 + 4);
        el2[4] = v.x * LOG2E; el2[5] = v.y * LOG2E; el2[6] = v.z * LOG2E; el2[7] = v.w * LOG2E;
        v = *reinterpret_cast<const float4*>(erow + tj * 16 + 8);
        el2[8] = v.x * LOG2E; el2[9] = v.y * LOG2E; el2[10] = v.z * LOG2E; el2[11] = v.w * LOG2E;
        v = *reinterpret_cast<const float4*>(erow + tj * 16 + 12);
        el2[12] = v.x * LOG2E; el2[13] = v.y * LOG2E; el2[14] = v.z * LOG2E; el2[15] = v.w * LOG2E;
    }

    // 16x16 tile: each element feeds one col-partial and one row-partial.
    float cs[16], rs[16];
    #pragma unroll
    for (int q = 0; q < 16; ++q) { cs[q] = 0.f; rs[q] = 0.f; }
    #pragma unroll
    for (int p = 0; p < 16; ++p) {
        const float dp = d[p];
        #pragma unroll
        for (int q = 0; q < 16; ++q) {
            const float v = __builtin_amdgcn_exp2f(dp * el2[q]);
            cs[q] += v;            // column q partial (sum over p)
            rs[p] += v;            // row p partial (sum over q)
        }
    }

    // LDS combine. Layout [i][j][16]: thread (i,j) block at float offset
    // (i*16+j)*16 = tid*16. Writes: b128, 2-way bank alias (free).
    __shared__ float lds[256 * 16];   // 16 KB
    const int wbase = tid * 16;

    // Pass A: column sums.  colsum[q] = sum_i lds[i*256 + q] (conflict-free).
    *reinterpret_cast<float4*>(&lds[wbase + 0])  = make_float4(cs[0], cs[1], cs[2], cs[3]);
    *reinterpret_cast<float4*>(&lds[wbase + 4])  = make_float4(cs[4], cs[5], cs[6], cs[7]);
    *reinterpret_cast<float4*>(&lds[wbase + 8])  = make_float4(cs[8], cs[9], cs[10], cs[11]);
    *reinterpret_cast<float4*>(&lds[wbase + 12]) = make_float4(cs[12], cs[13], cs[14], cs[15]);
    __syncthreads();
    float csum = 0.f;
    #pragma unroll
    for (int i2 = 0; i2 < 16; ++i2) csum += lds[i2 * 256 + tid];
    __syncthreads();

    // Pass B: row sums.  rowsum[p] = sum_j lds[(p>>4)*256 + j*16 + (p&15)]
    // (4-way bank alias on reads: ~free at this op count).
    *reinterpret_cast<float4*>(&lds[wbase + 0])  = make_float4(rs[0], rs[1], rs[2], rs[3]);
    *reinterpret_cast<float4*>(&lds[wbase + 4])  = make_float4(rs[4], rs[5], rs[6], rs[7]);
    *reinterpret_cast<float4*>(&lds[wbase + 8])  = make_float4(rs[8], rs[9], rs[10], rs[11]);
    *reinterpret_cast<float4*>(&lds[wbase + 12]) = make_float4(rs[12], rs[13], rs[14], rs[15]);
    __syncthreads();
    float rsum = 0.f;
    #pragma unroll
    for (int j2 = 0; j2 < 16; ++j2)
        rsum += lds[(tid >> 4) * 256 + j2 * 16 + (tid & 15)];

    ws[blk * DD + tid] = erow[tid] * csum / rsum;
}

// Phase 2 (R7): 64 blocks = (b, 32-wide q-slice); 256 threads = 8 t-chunks
// (16 t each) x 32 q. Halves the per-thread load-chain depth vs the 32-block
// version; lanes read 32 consecutive floats (two 128B segments/wave).
__global__ __launch_bounds__(256) void reduce_t_kernel(
    const float* __restrict__ ws, float* __restrict__ out) {
    __shared__ float red[8][32];
    const int b = blockIdx.x >> 3;
    const int qc = blockIdx.x & 7;
    const int qlane = threadIdx.x & 31;
    const int tc = threadIdx.x >> 5;         // 0..7
    const int q = qc * 32 + qlane;

    const float* p = ws + (b * TT + tc * 16) * DD + q;
    float a0 = 0.f, a1 = 0.f, a2 = 0.f, a3 = 0.f;
    #pragma unroll
    for (int t = 0; t < 16; t += 4) {
        a0 += p[(t + 0) * DD];
        a1 += p[(t + 1) * DD];
        a2 += p[(t + 2) * DD];
        a3 += p[(t + 3) * DD];
    }
    red[tc][qlane] = (a0 + a1) + (a2 + a3);
    __syncthreads();
    if (tc == 0) {
        float s = 0.f;
        #pragma unroll
        for (int u = 0; u < 8; ++u) s += red[u][qlane];
        out[b * DD + q] = s;
    }
}

extern "C" void kernel_launch(void* const* d_in, const int* in_sizes, int n_in,
                              void* d_out, int out_size, void* d_ws, size_t ws_size,
                              hipStream_t stream) {
    const float* dec = (const float*)d_in[0];  // [B, D] fp32
    const float* enc = (const float*)d_in[1];  // [B, T, D] fp32
    float* out = (float*)d_out;                // [B, D] fp32
    float* ws = (float*)d_ws;                  // >= BT*DD floats (1 MB)

    attn_tile_kernel<<<BT, 256, 0, stream>>>(dec, enc, ws);
    reduce_t_kernel<<<BB * 8, 256, 0, stream>>>(ws, out);
}

// Round 3
// 87.728 us; speedup vs baseline: 1.8070x; 1.8070x over previous
//
#include <hip/hip_runtime.h>

#define BB 8
#define TT 128
#define DD 256
#define BT (BB * TT)        // 1024 (b,t) pairs
#define LOG2E 1.44269504088896340736f

// R8: R5's proven scalar-state structure (no register arrays -> no spills),
// but exp goes to the FULL-RATE VALU instead of the slow trans pipe.
// Evidence: R5/R6 jointly show v_exp_f32 sustains only ~1 wave-instr/64cyc/SIMD
// (adding bpermutes cost 1:1 even at 8 waves/SIMD -> pipe-bound, not stalls).
// Inline exp2: rndne range-reduction + degree-7 Horner (7 FMA, rel err ~7e-9,
// better than v_exp_f32) + v_ldexp. ~12 VALU instrs x 2cyc = 24cyc/element
// vs ~68cyc for the v_exp path.
__device__ __forceinline__ float exp2_fast(float z) {
    const float r = __builtin_rintf(z);          // v_rndne_f32
    const float f = z - r;                       // f in [-0.5, 0.5]
    float p = 1.5252733804059840e-5f;            // ln2^7/7!
    p = __builtin_fmaf(p, f, 1.5403530393381609e-4f);   // ln2^6/6!
    p = __builtin_fmaf(p, f, 1.3333558146428443e-3f);   // ln2^5/5!
    p = __builtin_fmaf(p, f, 9.6181291076284772e-3f);   // ln2^4/4!
    p = __builtin_fmaf(p, f, 5.5504108664821580e-2f);   // ln2^3/3!
    p = __builtin_fmaf(p, f, 2.4022650695910072e-1f);   // ln2^2/2!
    p = __builtin_fmaf(p, f, 6.9314718055994531e-1f);   // ln2
    p = __builtin_fmaf(p, f, 1.0f);
    return ldexpf(p, (int)r);                    // v_cvt_i32 + v_ldexp_f32
}

// Phase 1: one block per (b,t), thread tid owns output column q = tid.
//   colsum[q] = sum_p exp(dec[p]*enc[q])   rowsum[q] = sum_r exp(dec[q]*enc[r])
// Symmetric recompute (2x elements) keeps live state to ~16 scalars: zero
// register arrays, zero LDS. Broadcast operands via uniform pointers
// (s_load_dwordx4 / constant cache).
__global__ __launch_bounds__(256, 4) void attn_sym_kernel(
    const float* __restrict__ dec,   // [B, D]
    const float* __restrict__ enc,   // [B, T, D]
    float* __restrict__ ws) {        // [BT, D] per-(b,t) contributions
    const int blk = blockIdx.x;              // b*TT + t
    const int b = blk >> 7;
    const int tid = threadIdx.x;             // q

    const float* __restrict__ drow = dec + b * DD;    // uniform pointer
    const float* __restrict__ erow = enc + blk * DD;  // uniform pointer

    const float dv = drow[tid];            // per-lane (vector load)
    const float ev = erow[tid];            // per-lane (vector load)
    const float dl2 = dv * LOG2E;          // rowsum arg: exp2(dl2 * e_r)
    const float el2 = ev * LOG2E;          // colsum arg: exp2(d_p * el2)

    float cs0 = 0.f, cs1 = 0.f, cs2 = 0.f, cs3 = 0.f;
    float rs0 = 0.f, rs1 = 0.f, rs2 = 0.f, rs3 = 0.f;
    #pragma unroll 4
    for (int k = 0; k < DD; k += 4) {
        // Uniform addresses -> scalar loads (no VMEM-vector pressure)
        float4 d4 = *reinterpret_cast<const float4*>(drow + k);
        float4 e4 = *reinterpret_cast<const float4*>(erow + k);
        cs0 += exp2_fast(d4.x * el2);
        cs1 += exp2_fast(d4.y * el2);
        cs2 += exp2_fast(d4.z * el2);
        cs3 += exp2_fast(d4.w * el2);
        rs0 += exp2_fast(dl2 * e4.x);
        rs1 += exp2_fast(dl2 * e4.y);
        rs2 += exp2_fast(dl2 * e4.z);
        rs3 += exp2_fast(dl2 * e4.w);
    }
    const float cs = (cs0 + cs1) + (cs2 + cs3);
    const float rs = (rs0 + rs1) + (rs2 + rs3);

    ws[blk * DD + tid] = ev * cs / rs;
}

// Phase 2: 64 blocks = (b, 32-wide q-slice); 256 threads = 8 t-chunks
// (16 t each) x 32 q. Lanes read consecutive q -> coalesced; ws is L2-resident.
__global__ __launch_bounds__(256) void reduce_t_kernel(
    const float* __restrict__ ws, float* __restrict__ out) {
    __shared__ float red[8][32];
    const int b = blockIdx.x >> 3;
    const int qc = blockIdx.x & 7;
    const int qlane = threadIdx.x & 31;
    const int tc = threadIdx.x >> 5;         // 0..7
    const int q = qc * 32 + qlane;

    const float* p = ws + (b * TT + tc * 16) * DD + q;
    float a0 = 0.f, a1 = 0.f, a2 = 0.f, a3 = 0.f;
    #pragma unroll
    for (int t = 0; t < 16; t += 4) {
        a0 += p[(t + 0) * DD];
        a1 += p[(t + 1) * DD];
        a2 += p[(t + 2) * DD];
        a3 += p[(t + 3) * DD];
    }
    red[tc][qlane] = (a0 + a1) + (a2 + a3);
    __syncthreads();
    if (tc == 0) {
        float s = 0.f;
        #pragma unroll
        for (int u = 0; u < 8; ++u) s += red[u][qlane];
        out[b * DD + q] = s;
    }
}

extern "C" void kernel_launch(void* const* d_in, const int* in_sizes, int n_in,
                              void* d_out, int out_size, void* d_ws, size_t ws_size,
                              hipStream_t stream) {
    const float* dec = (const float*)d_in[0];  // [B, D] fp32
    const float* enc = (const float*)d_in[1];  // [B, T, D] fp32
    float* out = (float*)d_out;                // [B, D] fp32
    float* ws = (float*)d_ws;                  // >= BT*DD floats (1 MB)

    attn_sym_kernel<<<BT, 256, 0, stream>>>(dec, enc, ws);
    reduce_t_kernel<<<BB * 8, 256, 0, stream>>>(ws, out);
}

// Round 4
// 82.018 us; speedup vs baseline: 1.9328x; 1.0696x over previous
//
#include <hip/hip_runtime.h>

#define BB 8
#define TT 128
#define DD 256
#define BT (BB * TT)        // 1024 (b,t) pairs
#define LOG2E 1.44269504088896340736f

// R9: dual-pipe exp. Ledger from R5-R8: timed region = ~41us harness workspace
// poison (fixed) + phase1 + ~5us phase2/launch. Phase1 R5 (v_exp/trans pipe)
// ~24us; R8 (polynomial/VALU pipe) 39.7us at VALUBusy=103%. The two exp
// implementations run on DIFFERENT pipes that co-issue -- so split the work:
// colsum exps on the trans pipe (v_exp_f32), rowsum exps on the VALU
// (degree-7 Horner exp2, validated in R8). Each pipe carries ~28-29K cyc/SIMD
// -> overlapped phase1 ~13-18us instead of 24/40.
__device__ __forceinline__ float exp2_fast(float z) {
    const float r = __builtin_rintf(z);          // v_rndne_f32
    const float f = z - r;                       // f in [-0.5, 0.5]
    float p = 1.5252733804059840e-5f;            // ln2^7/7!
    p = __builtin_fmaf(p, f, 1.5403530393381609e-4f);   // ln2^6/6!
    p = __builtin_fmaf(p, f, 1.3333558146428443e-3f);   // ln2^5/5!
    p = __builtin_fmaf(p, f, 9.6181291076284772e-3f);   // ln2^4/4!
    p = __builtin_fmaf(p, f, 5.5504108664821580e-2f);   // ln2^3/3!
    p = __builtin_fmaf(p, f, 2.4022650695910072e-1f);   // ln2^2/2!
    p = __builtin_fmaf(p, f, 6.9314718055994531e-1f);   // ln2
    p = __builtin_fmaf(p, f, 1.0f);
    return ldexpf(p, (int)r);                    // v_cvt_i32 + v_ldexp_f32
}

// Phase 1: one block per (b,t), thread tid owns output column q = tid.
//   colsum[q] = sum_p exp(dec[p]*enc[q])   rowsum[q] = sum_r exp(dec[q]*enc[r])
// Scalar live state only (no arrays -> no scratch, R7 lesson). Broadcast
// operands via uniform pointers (scalar loads / constant cache).
__global__ __launch_bounds__(256, 4) void attn_sym_kernel(
    const float* __restrict__ dec,   // [B, D]
    const float* __restrict__ enc,   // [B, T, D]
    float* __restrict__ ws) {        // [BT, D] per-(b,t) contributions
    const int blk = blockIdx.x;              // b*TT + t
    const int b = blk >> 7;
    const int tid = threadIdx.x;             // q

    const float* __restrict__ drow = dec + b * DD;    // uniform pointer
    const float* __restrict__ erow = enc + blk * DD;  // uniform pointer

    const float dv = drow[tid];            // per-lane (vector load)
    const float ev = erow[tid];            // per-lane (vector load)
    const float dl2 = dv * LOG2E;          // rowsum arg: exp2(dl2 * e_r)  [VALU poly]
    const float el2 = ev * LOG2E;          // colsum arg: exp2(d_p * el2)  [trans pipe]

    float cs0 = 0.f, cs1 = 0.f, cs2 = 0.f, cs3 = 0.f;
    float rs0 = 0.f, rs1 = 0.f, rs2 = 0.f, rs3 = 0.f;
    #pragma unroll 4
    for (int k = 0; k < DD; k += 4) {
        // Uniform addresses -> scalar loads (no VMEM-vector pressure)
        float4 d4 = *reinterpret_cast<const float4*>(drow + k);
        float4 e4 = *reinterpret_cast<const float4*>(erow + k);
        // trans-pipe stream (co-issues with VALU below)
        cs0 += __builtin_amdgcn_exp2f(d4.x * el2);
        cs1 += __builtin_amdgcn_exp2f(d4.y * el2);
        cs2 += __builtin_amdgcn_exp2f(d4.z * el2);
        cs3 += __builtin_amdgcn_exp2f(d4.w * el2);
        // VALU polynomial stream
        rs0 += exp2_fast(dl2 * e4.x);
        rs1 += exp2_fast(dl2 * e4.y);
        rs2 += exp2_fast(dl2 * e4.z);
        rs3 += exp2_fast(dl2 * e4.w);
    }
    const float cs = (cs0 + cs1) + (cs2 + cs3);
    const float rs = (rs0 + rs1) + (rs2 + rs3);

    ws[blk * DD + tid] = ev * cs / rs;
}

// Phase 2: 64 blocks = (b, 32-wide q-slice); 256 threads = 8 t-chunks
// (16 t each) x 32 q. Lanes read consecutive q -> coalesced; ws is L2-resident.
__global__ __launch_bounds__(256) void reduce_t_kernel(
    const float* __restrict__ ws, float* __restrict__ out) {
    __shared__ float red[8][32];
    const int b = blockIdx.x >> 3;
    const int qc = blockIdx.x & 7;
    const int qlane = threadIdx.x & 31;
    const int tc = threadIdx.x >> 5;         // 0..7
    const int q = qc * 32 + qlane;

    const float* p = ws + (b * TT + tc * 16) * DD + q;
    float a0 = 0.f, a1 = 0.f, a2 = 0.f, a3 = 0.f;
    #pragma unroll
    for (int t = 0; t < 16; t += 4) {
        a0 += p[(t + 0) * DD];
        a1 += p[(t + 1) * DD];
        a2 += p[(t + 2) * DD];
        a3 += p[(t + 3) * DD];
    }
    red[tc][qlane] = (a0 + a1) + (a2 + a3);
    __syncthreads();
    if (tc == 0) {
        float s = 0.f;
        #pragma unroll
        for (int u = 0; u < 8; ++u) s += red[u][qlane];
        out[b * DD + q] = s;
    }
}

extern "C" void kernel_launch(void* const* d_in, const int* in_sizes, int n_in,
                              void* d_out, int out_size, void* d_ws, size_t ws_size,
                              hipStream_t stream) {
    const float* dec = (const float*)d_in[0];  // [B, D] fp32
    const float* enc = (const float*)d_in[1];  // [B, T, D] fp32
    float* out = (float*)d_out;                // [B, D] fp32
    float* ws = (float*)d_ws;                  // >= BT*DD floats (1 MB)

    attn_sym_kernel<<<BT, 256, 0, stream>>>(dec, enc, ws);
    reduce_t_kernel<<<BB * 8, 256, 0, stream>>>(ws, out);
}

// Round 5
// 71.995 us; speedup vs baseline: 2.2019x; 1.1392x over previous
//
#include <hip/hip_runtime.h>

#define BB 8
#define TT 128
#define DD 256
#define BT (BB * TT)        // 1024 (b,t) pairs
#define SZ (BT * DD)        // 262144 floats per partial plane
#define LOG2E 1.44269504088896340736f

// R10: R5's proven v_exp scalar-state body (fastest exp path: trans ops
// serialize with VALU but cost only ~8-20cyc vs 28cyc for a VALU polynomial
// -- R8/R9 ruled the poly out) + R6's k-half block split for 8 waves/SIMD
// (R6 proved split+4-plane-combine correctness; its regression was the
// bpermutes, absent here). R5 ran at ~206 cyc/iter vs ~104 cyc of pure issue
// work at 4 waves/SIMD -> ~50% stall; doubling resident waves should absorb
// it. Per block: half the k-range, 32 iters x 8 v_exp.
__global__ __launch_bounds__(256, 8) void attn_half_kernel(
    const float* __restrict__ dec,   // [B, D]
    const float* __restrict__ enc,   // [B, T, D]
    float* __restrict__ ws) {        // [4][BT][DD]: {cs_h0, cs_h1, rs_h0, rs_h1}
    const int blk = blockIdx.x >> 1;     // b*TT + t
    const int h   = blockIdx.x & 1;      // k-half: p,r in [h*128, h*128+128)
    const int b   = blk >> 7;
    const int tid = threadIdx.x;         // q

    const float* __restrict__ dbase = dec + b * DD;
    const float* __restrict__ erow  = enc + blk * DD;
    const float* __restrict__ drh   = dbase + h * 128;  // uniform, this half
    const float* __restrict__ erh   = erow + h * 128;   // uniform, this half

    const float dv = dbase[tid];           // per-lane (vector load)
    const float ev = erow[tid];            // per-lane (vector load)
    const float dl2 = dv * LOG2E;          // rowsum arg: exp2(dl2 * e_r)
    const float el2 = ev * LOG2E;          // colsum arg: exp2(d_p * el2)

    float cs0 = 0.f, cs1 = 0.f, cs2 = 0.f, cs3 = 0.f;
    float rs0 = 0.f, rs1 = 0.f, rs2 = 0.f, rs3 = 0.f;
    #pragma unroll 4
    for (int k = 0; k < 128; k += 4) {
        // Uniform addresses -> scalar loads (constant cache), no VMEM pressure
        float4 d4 = *reinterpret_cast<const float4*>(drh + k);
        float4 e4 = *reinterpret_cast<const float4*>(erh + k);
        cs0 += __builtin_amdgcn_exp2f(d4.x * el2);
        cs1 += __builtin_amdgcn_exp2f(d4.y * el2);
        cs2 += __builtin_amdgcn_exp2f(d4.z * el2);
        cs3 += __builtin_amdgcn_exp2f(d4.w * el2);
        rs0 += __builtin_amdgcn_exp2f(dl2 * e4.x);
        rs1 += __builtin_amdgcn_exp2f(dl2 * e4.y);
        rs2 += __builtin_amdgcn_exp2f(dl2 * e4.z);
        rs3 += __builtin_amdgcn_exp2f(dl2 * e4.w);
    }
    const int o = blk * DD + tid;
    ws[h * SZ + o]       = (cs0 + cs1) + (cs2 + cs3);  // colsum partial
    ws[(2 + h) * SZ + o] = (rs0 + rs1) + (rs2 + rs3);  // rowsum partial
}

// Phase 2: 64 blocks = (b, 32-wide q-slice); 256 threads = 8 t-chunks
// (16 t each) x 32 q. Combines the k-halves (division is nonlinear -> must
// happen after both partials exist), multiplies by enc, sums over t. All 5
// streams coalesced (lanes read consecutive q); data L2-resident (~5 MB).
__global__ __launch_bounds__(256) void reduce_t_kernel(
    const float* __restrict__ ws, const float* __restrict__ enc,
    float* __restrict__ out) {
    __shared__ float red[8][32];
    const int b = blockIdx.x >> 3;
    const int qc = blockIdx.x & 7;
    const int qlane = threadIdx.x & 31;
    const int tc = threadIdx.x >> 5;         // 0..7
    const int q = qc * 32 + qlane;

    const int base = (b * TT + tc * 16) * DD + q;
    float a0 = 0.f, a1 = 0.f, a2 = 0.f, a3 = 0.f;
    #pragma unroll
    for (int t = 0; t < 16; t += 4) {
        const int i0 = base + (t + 0) * DD;
        const int i1 = base + (t + 1) * DD;
        const int i2 = base + (t + 2) * DD;
        const int i3 = base + (t + 3) * DD;
        a0 += enc[i0] * (ws[i0] + ws[SZ + i0]) / (ws[2 * SZ + i0] + ws[3 * SZ + i0]);
        a1 += enc[i1] * (ws[i1] + ws[SZ + i1]) / (ws[2 * SZ + i1] + ws[3 * SZ + i1]);
        a2 += enc[i2] * (ws[i2] + ws[SZ + i2]) / (ws[2 * SZ + i2] + ws[3 * SZ + i2]);
        a3 += enc[i3] * (ws[i3] + ws[SZ + i3]) / (ws[2 * SZ + i3] + ws[3 * SZ + i3]);
    }
    red[tc][qlane] = (a0 + a1) + (a2 + a3);
    __syncthreads();
    if (tc == 0) {
        float s = 0.f;
        #pragma unroll
        for (int u = 0; u < 8; ++u) s += red[u][qlane];
        out[b * DD + q] = s;
    }
}

extern "C" void kernel_launch(void* const* d_in, const int* in_sizes, int n_in,
                              void* d_out, int out_size, void* d_ws, size_t ws_size,
                              hipStream_t stream) {
    const float* dec = (const float*)d_in[0];  // [B, D] fp32
    const float* enc = (const float*)d_in[1];  // [B, T, D] fp32
    float* out = (float*)d_out;                // [B, D] fp32
    float* ws = (float*)d_ws;                  // >= 4*BT*DD floats (4 MB)

    attn_half_kernel<<<BT * 2, 256, 0, stream>>>(dec, enc, ws);
    reduce_t_kernel<<<BB * 8, 256, 0, stream>>>(ws, enc, out);
}